// Round 4
// baseline (880.335 us; speedup 1.0000x reference)
//
#include <hip/hip_runtime.h>
#include <math.h>

#define NS 150
#define LDW 152
#define NPACK 11848   // sum of padded packed upper-tri row lengths
#define NT 40
#define MS 200
#define MT 30
#define N_SWEEPS 6
#define JITTER 0.1f

// packed upper-tri storage: row r holds cols [r&~3, 152), 16B-aligned start.
__device__ __forceinline__ int rs_off(int r) {
    int g = r >> 2, rm = r & 3;
    return LDW * r - 8 * g * (g - 1) - 4 * rm * g;
}

// K1: build S, T, TsT (spatial-major test kernel), Tt
__global__ void build_kernels(const float* __restrict__ sc, const float* __restrict__ tc,
                              const float* __restrict__ tsc, const float* __restrict__ ttc,
                              const float* __restrict__ lll, const float* __restrict__ lle,
                              const float* __restrict__ llt,
                              float* __restrict__ S, float* __restrict__ T,
                              float* __restrict__ TsT, float* __restrict__ Tt) {
    int idx = blockIdx.x * blockDim.x + threadIdx.x;
    float inv_ll2 = expf(-2.0f * lll[0]);
    float inv_le2 = expf(-2.0f * lle[0]);
    float inv_lt2 = expf(-2.0f * llt[0]);
    if (idx < NS * NS) {
        int i = idx / NS, j = idx % NS;
        float d0 = sc[i*3+0] - sc[j*3+0];
        float d1 = sc[i*3+1] - sc[j*3+1];
        float d2 = sc[i*3+2] - sc[j*3+2];
        float v = expf(-((d0*d0 + d1*d1) * inv_ll2 + d2*d2 * inv_le2));
        if (i == j) v += JITTER;
        S[idx] = v;
    } else if (idx < NS*NS + NT*NT) {
        int k = idx - NS*NS;
        int i = k / NT, j = k % NT;
        float dt = tc[i] - tc[j];
        float v = expf(-(dt*dt) * inv_lt2);
        if (i == j) v += JITTER;
        T[k] = v;
    } else if (idx < NS*NS + NT*NT + NS*MS) {
        int t = idx - NS*NS - NT*NT;
        int k = t / MS, c = t % MS;     // k: train-space idx, c: test idx
        float d0 = tsc[c*3+0] - sc[k*3+0];
        float d1 = tsc[c*3+1] - sc[k*3+1];
        float d2 = tsc[c*3+2] - sc[k*3+2];
        TsT[t] = expf(-((d0*d0 + d1*d1) * inv_ll2 + d2*d2 * inv_le2));
    } else if (idx < NS*NS + NT*NT + NS*MS + MT*NT) {
        int k = idx - NS*NS - NT*NT - NS*MS;
        int i = k / NT, j = k % NT;
        float dt = ttc[i] - tc[j];
        Tt[k] = expf(-(dt*dt) * inv_lt2);
    }
}

// K2: single-wave cyclic Jacobi eigh of 40x40 T. V kept TRANSPOSED (rows = eigvec
//     columns, padded to 44) so V-updates are contiguous float4 row ops.
//     Tail: Amat = Tt * V.
__global__ void __launch_bounds__(64) jacobi64(const float* __restrict__ T,
                                               const float* __restrict__ Tt,
                                               float* __restrict__ Vt, float* __restrict__ wt,
                                               float* __restrict__ Amat) {
    __shared__ __align__(16) float A[NT][NT + 1];
    __shared__ __align__(16) float Vts[NT][44];     // Vts[j][k] = V[k][j]
    __shared__ __align__(16) float4 prm[NT/2];      // (c, s, bits(p), bits(q))
    int l = threadIdx.x;
    for (int idx = l; idx < NT*NT; idx += 64) A[idx/NT][idx%NT] = T[idx];
    for (int idx = l; idx < NT*44; idx += 64) {
        int jr = idx / 44, k = idx - jr*44;
        Vts[jr][k] = (jr == k) ? 1.0f : 0.0f;
    }
    __syncthreads();
    const int rounds = N_SWEEPS * (NT - 1);
    for (int rd = 0; rd < rounds; ++rd) {
        int rr = rd % (NT - 1);
        if (l < NT/2) {
            int i0 = l, i1 = NT - 1 - l;
            int p = (i0 == 0) ? 0 : ((i0 - 1 + rr) % (NT - 1)) + 1;
            int q = ((i1 - 1 + rr) % (NT - 1)) + 1;
            if (p > q) { int tsw = p; p = q; q = tsw; }
            float app = A[p][p], aqq = A[q][q], apq = A[p][q];
            float c, s;
            if (apq == 0.0f) { c = 1.0f; s = 0.0f; }
            else {
                float tau = (aqq - app) / (2.0f * apq);
                float tt = ((tau >= 0.0f) ? 1.0f : -1.0f) / (fabsf(tau) + sqrtf(1.0f + tau*tau));
                c = rsqrtf(1.0f + tt*tt);
                s = tt * c;
            }
            prm[l] = make_float4(c, s, __int_as_float(p), __int_as_float(q));
        }
        __syncthreads();
        // fused left+right rotation on A: 20x20 grid of disjoint 2x2 blocks
        for (int t = l; t < 400; t += 64) {
            int bi = t / 20, bj = t - bi*20;
            float4 Pi = prm[bi], Pj = prm[bj];
            int pi = __float_as_int(Pi.z), qi = __float_as_int(Pi.w);
            int pj = __float_as_int(Pj.z), qj = __float_as_int(Pj.w);
            float ci = Pi.x, si = Pi.y, cj = Pj.x, sj = Pj.y;
            float a00 = A[pi][pj], a01 = A[pi][qj], a10 = A[qi][pj], a11 = A[qi][qj];
            float b00 = ci*a00 - si*a10, b01 = ci*a01 - si*a11;
            float b10 = si*a00 + ci*a10, b11 = si*a01 + ci*a11;
            A[pi][pj] = cj*b00 - sj*b01; A[pi][qj] = sj*b00 + cj*b01;
            A[qi][pj] = cj*b10 - sj*b11; A[qi][qj] = sj*b10 + cj*b11;
        }
        // V update (independent of A-phase): rows pj,qj of Vts, float4 chunks
        for (int t = l; t < 200; t += 64) {
            int pr = t / 10, ch = (t - pr*10) << 2;
            float4 P = prm[pr];
            int pj = __float_as_int(P.z), qj = __float_as_int(P.w);
            float c = P.x, s = P.y;
            float4 vp = *(float4*)&Vts[pj][ch];
            float4 vq = *(float4*)&Vts[qj][ch];
            float4 np, nq;
            np.x = c*vp.x - s*vq.x; nq.x = s*vp.x + c*vq.x;
            np.y = c*vp.y - s*vq.y; nq.y = s*vp.y + c*vq.y;
            np.z = c*vp.z - s*vq.z; nq.z = s*vp.z + c*vq.z;
            np.w = c*vp.w - s*vq.w; nq.w = s*vp.w + c*vq.w;
            *(float4*)&Vts[pj][ch] = np;
            *(float4*)&Vts[qj][ch] = nq;
        }
        __syncthreads();
    }
    // epilogue: Vt[t*NT+j] = V[t][j] = Vts[j][t]; wt; Amat = Tt*V
    for (int idx = l; idx < NT*NT; idx += 64) {
        int t = idx / NT, jj = idx - t*NT;
        Vt[idx] = Vts[jj][t];
    }
    if (l < NT) wt[l] = A[l][l];
    for (int idx = l; idx < MT*NT; idx += 64) {
        int it = idx / NT, jj = idx - it*NT;
        float s = 0.0f;
        for (int t2 = 0; t2 < NT; ++t2) s += Tt[it*NT + t2] * Vts[jj][t2];
        Amat[idx] = s;
    }
}

// K3: per-j upper Cholesky (raw rank-1 form, 1 barrier/step). RHS g folded in as
//     column 150 so the y-solve rides the trailing update. Scaled U + y written out.
__global__ void __launch_bounds__(256) chol40(const float* __restrict__ S,
        const float* __restrict__ wt, const float* __restrict__ Vt,
        const float* __restrict__ st, const float* __restrict__ lnv,
        float* __restrict__ Ug, float* __restrict__ yg) {
    __shared__ __align__(16) float Mp[NPACK];
    __shared__ float dvs[NS];
    int j = blockIdx.x, tid = threadIdx.x;
    float wtj = wt[j];
    float nv = expf(lnv[0]);
    // init packed M: cols [rbase,150) = wtj*S (+nv on diag); col 150 = g; col 151 = 0
    for (int idx = tid; idx < NS*LDW; idx += 256) {
        int r = idx / LDW, c = idx - r*LDW;
        int rbase = r & ~3;
        if (c < rbase) continue;
        float v = 0.0f;
        if (c < NS) v = wtj * S[r*NS + c];
        if (c == r) v += nv;
        Mp[rs_off(r) + c - rbase] = v;
    }
    for (int r = tid; r < NS; r += 256) {
        float acc = 0.0f;
        for (int t = 0; t < NT; ++t) acc += Vt[t*NT + j] * st[r*NT + t];
        Mp[rs_off(r) + 150 - (r & ~3)] = acc;
    }
    __syncthreads();
    for (int k = 0; k < NS - 1; ++k) {
        int rowK = rs_off(k) - (k & ~3);
        float mkk = Mp[rowK + k];
        float irkk = 1.0f / mkk;
        int cb = (k + 1) & ~3;
        int W4 = (LDW - cb) >> 2;
        int qd = tid / W4;
        int ci = tid - qd * W4;
        int r = k + 1 + qd;
        int dr = 256 / W4, dc = 256 - dr * W4;
        while (r < NS) {
            int C = cb + (ci << 2);
            int rbase = r & ~3;
            if (C >= rbase) {
                int g = r >> 2, rm = r & 3;
                int addr = LDW*r - 8*g*(g-1) - 4*rm*g + C - rbase;
                float fac = Mp[rowK + r] * irkk;
                float4 mk = *(float4*)&Mp[rowK + C];
                float4 v = *(float4*)&Mp[addr];
                v.x -= fac * mk.x; v.y -= fac * mk.y;
                v.z -= fac * mk.z; v.w -= fac * mk.w;
                *(float4*)&Mp[addr] = v;
            }
            ci += dc; r += dr;
            if (ci >= W4) { ci -= W4; ++r; }
        }
        __syncthreads();
    }
    // epilogue: diag holds raw pivots; dv = 1/sqrt(pivot); y = braw*dv; scale U
    for (int r = tid; r < NS; r += 256)
        dvs[r] = rsqrtf(Mp[rs_off(r) + r - (r & ~3)]);
    __syncthreads();
    for (int k = tid; k < NS; k += 256)
        yg[j*LDW + k] = Mp[rs_off(k) + 150 - (k & ~3)] * dvs[k];
    for (int idx = tid; idx < NS*LDW; idx += 256) {
        int r = idx / LDW, c = idx - r*LDW;
        int rbase = r & ~3;
        if (c < rbase) continue;
        int t = rs_off(r) + c - rbase;
        float v = Mp[t];
        float dvr = dvs[r];
        v = (c == r) ? dvr : ((c > r) ? v * dvr : v);
        Ug[(size_t)j*NPACK + t] = v;
    }
}

// K4: 160 blocks (j, 50-col group), 1 wave each. Forward solve U^T u = ts_c with
//     u[] in registers, float4 broadcast row reads. q = sum u^2, R = sum u*y.
__global__ void __launch_bounds__(64) trsm160(const float* __restrict__ Ug,
        const float* __restrict__ yg, const float* __restrict__ TsT,
        float* __restrict__ q, float* __restrict__ R) {
    __shared__ __align__(16) float Up[NPACK];
    __shared__ float yv[NS];
    int bid = blockIdx.x;
    int j = bid >> 2, grp = bid & 3;
    int lane = threadIdx.x;
    int c = grp * 50 + lane;
    bool active = (lane < 50);
    int cc = active ? c : 0;
    for (int t4 = lane * 4; t4 < NPACK; t4 += 256)
        *(float4*)&Up[t4] = *(const float4*)&Ug[(size_t)j*NPACK + t4];
    for (int t = lane; t < NS; t += 64) yv[t] = yg[j*LDW + t];
    __syncthreads();
    float u[LDW];
    #pragma unroll
    for (int k = 0; k < NS; ++k) u[k] = TsT[k*MS + cc];
    u[150] = 0.0f; u[151] = 0.0f;
    float qa = 0.0f, ra = 0.0f;
    #pragma unroll
    for (int k = 0; k < NS; ++k) {
        const int base = rs_off(k) - (k & ~3);
        float uk = u[k] * Up[base + k];      // diag slot holds 1/d
        qa += uk * uk;
        ra += uk * yv[k];
        const int kp = k + 1;
        const int ka = (kp + 3) & ~3;
        #pragma unroll
        for (int t = kp; t < ((ka < NS) ? ka : NS); ++t)
            u[t] -= Up[base + t] * uk;
        #pragma unroll
        for (int t = ka; t < NS; t += 4) {
            float4 w = *(const float4*)&Up[base + t];
            u[t+0] -= w.x * uk; u[t+1] -= w.y * uk;
            u[t+2] -= w.z * uk; u[t+3] -= w.w * uk;
        }
    }
    if (active) {
        q[j*MS + c] = qa;
        R[j*MS + c] = ra;
    }
}

// K5: outputs. yPred[is][it] = sum_j A[it][j]*R[j][is];
//              yVar [is][it] = sig2 - sum_j A[it][j]^2 * q[j][is]
__global__ void finalize(const float* __restrict__ A, const float* __restrict__ q,
                         const float* __restrict__ R, const float* __restrict__ lsv,
                         float* __restrict__ out) {
    int idx = blockIdx.x * blockDim.x + threadIdx.x;
    if (idx >= MS * MT) return;
    int is = idx / MT, it = idx % MT;
    float sp = 0.0f, sv = 0.0f;
    for (int j = 0; j < NT; ++j) {
        float a = A[it*NT + j];
        sp += a * R[j*MS + is];
        sv += a*a * q[j*MS + is];
    }
    float sigv = expf(lsv[0]);
    out[idx] = sp;
    out[MS*MT + idx] = sigv - sv;
}

extern "C" void kernel_launch(void* const* d_in, const int* in_sizes, int n_in,
                              void* d_out, int out_size, void* d_ws, size_t ws_size,
                              hipStream_t stream) {
    const float* sc  = (const float*)d_in[0];   // 150x3
    const float* tc  = (const float*)d_in[1];   // 40x1
    const float* st  = (const float*)d_in[2];   // 150x40
    const float* tsc = (const float*)d_in[3];   // 200x3
    const float* ttc = (const float*)d_in[4];   // 30x1
    const float* lll = (const float*)d_in[5];
    const float* lle = (const float*)d_in[6];
    const float* llt = (const float*)d_in[7];
    const float* lnv = (const float*)d_in[8];
    const float* lsv = (const float*)d_in[9];
    float* out = (float*)d_out;

    float* ws   = (float*)d_ws;
    float* S    = ws;                 // 22500
    float* T    = S    + 22500;       // 1600
    float* TsT  = T    + 1600;        // 30000
    float* Tt   = TsT  + 30000;       // 1200
    float* Vt   = Tt   + 1200;        // 1600
    float* wt   = Vt   + 1600;        // 40
    float* Amat = wt   + 40;          // 1200
    float* q    = Amat + 1200;        // 8000
    float* R    = q    + 8000;        // 8000
    float* yg   = R    + 8000;        // 40*152 = 6080
    float* Ug   = yg   + 6080;        // 40*11848 = 473920

    int total1 = NS*NS + NT*NT + NS*MS + MT*NT;   // 55300
    hipLaunchKernelGGL(build_kernels, dim3((total1 + 255)/256), dim3(256), 0, stream,
                       sc, tc, tsc, ttc, lll, lle, llt, S, T, TsT, Tt);
    hipLaunchKernelGGL(jacobi64, dim3(1), dim3(64), 0, stream, T, Tt, Vt, wt, Amat);
    hipLaunchKernelGGL(chol40, dim3(NT), dim3(256), 0, stream,
                       S, wt, Vt, st, lnv, Ug, yg);
    hipLaunchKernelGGL(trsm160, dim3(NT*4), dim3(64), 0, stream,
                       Ug, yg, TsT, q, R);
    hipLaunchKernelGGL(finalize, dim3((MS*MT + 255)/256), dim3(256), 0, stream,
                       Amat, q, R, lsv, out);
}

// Round 5
// 567.092 us; speedup vs baseline: 1.5524x; 1.5524x over previous
//
#include <hip/hip_runtime.h>
#include <math.h>

#define NS 150
#define LDW 152
#define NPACK 11848   // sum of padded packed upper-tri row lengths
#define NT 40
#define MS 200
#define MT 30
#define N_SWEEPS 6
#define JITTER 0.1f

// packed upper-tri storage: row r holds cols [r&~3, 152), 16B-aligned start.
__device__ __forceinline__ int rs_off(int r) {
    int g = r >> 2, rm = r & 3;
    return LDW * r - 8 * g * (g - 1) - 4 * rm * g;
}

// K1: build S, T, TsT (spatial-major test kernel), Tt
__global__ void build_kernels(const float* __restrict__ sc, const float* __restrict__ tc,
                              const float* __restrict__ tsc, const float* __restrict__ ttc,
                              const float* __restrict__ lll, const float* __restrict__ lle,
                              const float* __restrict__ llt,
                              float* __restrict__ S, float* __restrict__ T,
                              float* __restrict__ TsT, float* __restrict__ Tt) {
    int idx = blockIdx.x * blockDim.x + threadIdx.x;
    float inv_ll2 = expf(-2.0f * lll[0]);
    float inv_le2 = expf(-2.0f * lle[0]);
    float inv_lt2 = expf(-2.0f * llt[0]);
    if (idx < NS * NS) {
        int i = idx / NS, j = idx % NS;
        float d0 = sc[i*3+0] - sc[j*3+0];
        float d1 = sc[i*3+1] - sc[j*3+1];
        float d2 = sc[i*3+2] - sc[j*3+2];
        float v = expf(-((d0*d0 + d1*d1) * inv_ll2 + d2*d2 * inv_le2));
        if (i == j) v += JITTER;
        S[idx] = v;
    } else if (idx < NS*NS + NT*NT) {
        int k = idx - NS*NS;
        int i = k / NT, j = k % NT;
        float dt = tc[i] - tc[j];
        float v = expf(-(dt*dt) * inv_lt2);
        if (i == j) v += JITTER;
        T[k] = v;
    } else if (idx < NS*NS + NT*NT + NS*MS) {
        int t = idx - NS*NS - NT*NT;
        int k = t / MS, c = t % MS;     // k: train-space idx, c: test idx
        float d0 = tsc[c*3+0] - sc[k*3+0];
        float d1 = tsc[c*3+1] - sc[k*3+1];
        float d2 = tsc[c*3+2] - sc[k*3+2];
        TsT[t] = expf(-((d0*d0 + d1*d1) * inv_ll2 + d2*d2 * inv_le2));
    } else if (idx < NS*NS + NT*NT + NS*MS + MT*NT) {
        int k = idx - NS*NS - NT*NT - NS*MS;
        int i = k / NT, j = k % NT;
        float dt = ttc[i] - tc[j];
        Tt[k] = expf(-(dt*dt) * inv_lt2);
    }
}

__device__ __forceinline__ void jac_params(const float A[NT][NT+1], float4* dst,
                                           int i, int rr) {
    int i0 = i, i1 = NT - 1 - i;
    int p = (i0 == 0) ? 0 : ((i0 - 1 + rr) % (NT - 1)) + 1;
    int q = ((i1 - 1 + rr) % (NT - 1)) + 1;
    if (p > q) { int tsw = p; p = q; q = tsw; }
    float app = A[p][p], aqq = A[q][q], apq = A[p][q];
    float c, s;
    if (apq == 0.0f) { c = 1.0f; s = 0.0f; }
    else {
        float tau = (aqq - app) / (2.0f * apq);
        float tt = ((tau >= 0.0f) ? 1.0f : -1.0f) / (fabsf(tau) + sqrtf(1.0f + tau*tau));
        c = rsqrtf(1.0f + tt*tt);
        s = tt * c;
    }
    dst[i] = make_float4(c, s, __int_as_float(p), __int_as_float(q));
}

// K2: 256-thread cyclic Jacobi eigh of 40x40 T. Fused 2x2 A-rotation; transposed V
//     (float4 rows); params for round rd+1 computed by lanes 200-219 during V-phase
//     (double-buffered). Tail: Amat = Tt * V.
__global__ void __launch_bounds__(256) jacobi(const float* __restrict__ T,
                                              const float* __restrict__ Tt,
                                              float* __restrict__ Vt, float* __restrict__ wt,
                                              float* __restrict__ Amat) {
    __shared__ __align__(16) float A[NT][NT + 1];
    __shared__ __align__(16) float Vts[NT][44];     // Vts[j][k] = V[k][j]
    __shared__ __align__(16) float4 prm[2][NT/2];   // (c, s, bits(p), bits(q))
    int tid = threadIdx.x;
    for (int idx = tid; idx < NT*NT; idx += 256) A[idx/NT][idx%NT] = T[idx];
    for (int idx = tid; idx < NT*44; idx += 256) {
        int jr = idx / 44, k = idx - jr*44;
        Vts[jr][k] = (jr == k) ? 1.0f : 0.0f;
    }
    __syncthreads();
    if (tid >= 200 && tid < 220) jac_params(A, prm[0], tid - 200, 0);
    __syncthreads();
    const int rounds = N_SWEEPS * (NT - 1);
    for (int rd = 0; rd < rounds; ++rd) {
        const float4* cur = prm[rd & 1];
        float4* nxt = prm[(rd + 1) & 1];
        // fused left+right rotation on A: 20x20 grid of disjoint 2x2 blocks
        for (int t = tid; t < 400; t += 256) {
            int bi = t / 20, bj = t - bi*20;
            float4 Pi = cur[bi], Pj = cur[bj];
            int pi = __float_as_int(Pi.z), qi = __float_as_int(Pi.w);
            int pj = __float_as_int(Pj.z), qj = __float_as_int(Pj.w);
            float ci = Pi.x, si = Pi.y, cj = Pj.x, sj = Pj.y;
            float a00 = A[pi][pj], a01 = A[pi][qj], a10 = A[qi][pj], a11 = A[qi][qj];
            float b00 = ci*a00 - si*a10, b01 = ci*a01 - si*a11;
            float b10 = si*a00 + ci*a10, b11 = si*a01 + ci*a11;
            A[pi][pj] = cj*b00 - sj*b01; A[pi][qj] = sj*b00 + cj*b01;
            A[qi][pj] = cj*b10 - sj*b11; A[qi][qj] = sj*b10 + cj*b11;
        }
        __syncthreads();
        // V update (doesn't touch A) in parallel with params for next round
        if (tid < 200) {
            int pr = tid / 10, ch = (tid - pr*10) << 2;
            float4 P = cur[pr];
            int pj = __float_as_int(P.z), qj = __float_as_int(P.w);
            float c = P.x, s = P.y;
            float4 vp = *(float4*)&Vts[pj][ch];
            float4 vq = *(float4*)&Vts[qj][ch];
            float4 np, nq;
            np.x = c*vp.x - s*vq.x; nq.x = s*vp.x + c*vq.x;
            np.y = c*vp.y - s*vq.y; nq.y = s*vp.y + c*vq.y;
            np.z = c*vp.z - s*vq.z; nq.z = s*vp.z + c*vq.z;
            np.w = c*vp.w - s*vq.w; nq.w = s*vp.w + c*vq.w;
            *(float4*)&Vts[pj][ch] = np;
            *(float4*)&Vts[qj][ch] = nq;
        } else if (tid < 220) {
            jac_params(A, nxt, tid - 200, (rd + 1) % (NT - 1));
        }
        __syncthreads();
    }
    for (int idx = tid; idx < NT*NT; idx += 256) {
        int t = idx / NT, jj = idx - t*NT;
        Vt[idx] = Vts[jj][t];
    }
    if (tid < NT) wt[tid] = A[tid][tid];
    for (int idx = tid; idx < MT*NT; idx += 256) {
        int it = idx / NT, jj = idx - it*NT;
        float s = 0.0f;
        for (int t2 = 0; t2 < NT; ++t2) s += Tt[it*NT + t2] * Vts[jj][t2];
        Amat[idx] = s;
    }
}

// K3: per-j upper factorization, rank-4 panels (2 barriers / 4 pivots). Raw Gaussian
//     form (no sqrt in loop); panel rows staged in LDS scratch to avoid RAW races;
//     elimination scalars computed redundantly per thread. RHS g rides as col 150.
__global__ void __launch_bounds__(256) chol40(const float* __restrict__ S,
        const float* __restrict__ wt, const float* __restrict__ Vt,
        const float* __restrict__ st, const float* __restrict__ lnv,
        float* __restrict__ Ug, float* __restrict__ yg) {
    __shared__ __align__(16) float Mp[NPACK];
    __shared__ __align__(16) float Pr[4][LDW];
    __shared__ float dvs[NS];
    int j = blockIdx.x, tid = threadIdx.x;
    float wtj = wt[j];
    float nv = expf(lnv[0]);
    for (int idx = tid; idx < NS*LDW; idx += 256) {
        int r = idx / LDW, c = idx - r*LDW;
        int rbase = r & ~3;
        if (c < rbase) continue;
        float v = 0.0f;
        if (c < NS) v = wtj * S[r*NS + c];
        if (c == r) v += nv;
        Mp[rs_off(r) + c - rbase] = v;
    }
    for (int r = tid; r < NS; r += 256) {
        float acc = 0.0f;
        for (int t = 0; t < NT; ++t) acc += Vt[t*NT + j] * st[r*NT + t];
        Mp[rs_off(r) + 150 - (r & ~3)] = acc;
    }
    __syncthreads();
    for (int k0 = 0; k0 < NS - 1; k0 += 4) {
        int P = NS - k0; if (P > 4) P = 4;
        int span = LDW - k0;        // k0 % 4 == 0 -> all panel rows have rbase = k0
        int W4 = span >> 2;
        // phase A: stage panel rows into scratch
        int citems = P * W4;
        for (int t = tid; t < citems; t += 256) {
            int pr = t / W4, ch = (t - pr*W4) << 2;
            *(float4*)&Pr[pr][ch] = *(float4*)&Mp[rs_off(k0 + pr) + ch];
        }
        __syncthreads();
        // hoisted panel elimination scalars (redundant per thread)
        float d0 = Pr[0][0];
        float i0 = 1.0f / d0;
        float B01 = (P > 1) ? Pr[0][1] : 0.0f;
        float B02 = (P > 2) ? Pr[0][2] : 0.0f;
        float B03 = (P > 3) ? Pr[0][3] : 0.0f;
        float l10 = B01 * i0, l20 = B02 * i0, l30 = B03 * i0;
        float d1 = (P > 1) ? (Pr[1][1] - l10*B01) : 1.0f;
        float i1 = 1.0f / d1;
        float B12 = (P > 2) ? (Pr[1][2] - l10*B02) : 0.0f;
        float B13 = (P > 3) ? (Pr[1][3] - l10*B03) : 0.0f;
        float l21 = B12 * i1, l31 = B13 * i1;
        float d2 = (P > 2) ? (Pr[2][2] - l20*B02 - l21*B12) : 1.0f;
        float i2 = 1.0f / d2;
        float B23 = (P > 3) ? (Pr[2][3] - l20*B03 - l21*B13) : 0.0f;
        float l32 = B23 * i2;
        float d3 = (P > 3) ? (Pr[3][3] - l30*B03 - l31*B13 - l32*B23) : 1.0f;
        float i3 = 1.0f / d3;
        // phase B: rank-P trailing update, rows (k0, NS) x f4 cols [k0,152)
        int items = (NS - 1 - k0) * W4;
        for (int t = tid; t < items; t += 256) {
            int rq = t / W4, ci = t - rq*W4;
            int r = k0 + 1 + rq;
            int C = k0 + (ci << 2);
            int rbase = r & ~3;
            if (C < rbase) continue;
            int E = r - k0; if (E > P) E = P;
            int rc = r - k0;
            int addr = rs_off(r) + C - rbase;
            float4 v = *(float4*)&Mp[addr];
            float e0 = Pr[0][rc];
            float f0 = e0 * i0;
            float4 m0 = *(float4*)&Pr[0][C - k0];
            v.x -= f0*m0.x; v.y -= f0*m0.y; v.z -= f0*m0.z; v.w -= f0*m0.w;
            if (E > 1) {
                float e1 = Pr[1][rc] - l10*e0;
                float f1 = e1 * i1;
                float4 m1 = *(float4*)&Pr[1][C - k0];
                m1.x -= l10*m0.x; m1.y -= l10*m0.y; m1.z -= l10*m0.z; m1.w -= l10*m0.w;
                v.x -= f1*m1.x; v.y -= f1*m1.y; v.z -= f1*m1.z; v.w -= f1*m1.w;
                if (E > 2) {
                    float e2 = Pr[2][rc] - l20*e0 - l21*e1;
                    float f2 = e2 * i2;
                    float4 m2 = *(float4*)&Pr[2][C - k0];
                    m2.x -= l20*m0.x + l21*m1.x; m2.y -= l20*m0.y + l21*m1.y;
                    m2.z -= l20*m0.z + l21*m1.z; m2.w -= l20*m0.w + l21*m1.w;
                    v.x -= f2*m2.x; v.y -= f2*m2.y; v.z -= f2*m2.z; v.w -= f2*m2.w;
                    if (E > 3) {
                        float e3 = Pr[3][rc] - l30*e0 - l31*e1 - l32*e2;
                        float f3 = e3 * i3;
                        float4 m3 = *(float4*)&Pr[3][C - k0];
                        m3.x -= l30*m0.x + l31*m1.x + l32*m2.x;
                        m3.y -= l30*m0.y + l31*m1.y + l32*m2.y;
                        m3.z -= l30*m0.z + l31*m1.z + l32*m2.z;
                        m3.w -= l30*m0.w + l31*m1.w + l32*m2.w;
                        v.x -= f3*m3.x; v.y -= f3*m3.y; v.z -= f3*m3.z; v.w -= f3*m3.w;
                    }
                }
            }
            *(float4*)&Mp[addr] = v;
        }
        __syncthreads();
    }
    // epilogue: diag holds raw pivots; dv = 1/sqrt(pivot); y = braw*dv; scale U
    for (int r = tid; r < NS; r += 256)
        dvs[r] = rsqrtf(Mp[rs_off(r) + r - (r & ~3)]);
    __syncthreads();
    for (int k = tid; k < NS; k += 256)
        yg[j*LDW + k] = Mp[rs_off(k) + 150 - (k & ~3)] * dvs[k];
    for (int idx = tid; idx < NS*LDW; idx += 256) {
        int r = idx / LDW, c = idx - r*LDW;
        int rbase = r & ~3;
        if (c < rbase) continue;
        int t = rs_off(r) + c - rbase;
        float v = Mp[t];
        float dvr = dvs[r];
        v = (c == r) ? dvr : ((c > r) ? v * dvr : v);
        Ug[(size_t)j*NPACK + t] = v;
    }
}

// K4: 160 blocks (j, 50-col group), 1 wave each. Forward solve U^T u = ts_c with
//     u[] in registers, float4 broadcast row reads. q = sum u^2, R = sum u*y.
__global__ void __launch_bounds__(64) trsm160(const float* __restrict__ Ug,
        const float* __restrict__ yg, const float* __restrict__ TsT,
        float* __restrict__ q, float* __restrict__ R) {
    __shared__ __align__(16) float Up[NPACK];
    __shared__ float yv[NS];
    int bid = blockIdx.x;
    int j = bid >> 2, grp = bid & 3;
    int lane = threadIdx.x;
    int c = grp * 50 + lane;
    bool active = (lane < 50);
    int cc = active ? c : 0;
    for (int t4 = lane * 4; t4 < NPACK; t4 += 256)
        *(float4*)&Up[t4] = *(const float4*)&Ug[(size_t)j*NPACK + t4];
    for (int t = lane; t < NS; t += 64) yv[t] = yg[j*LDW + t];
    __syncthreads();
    float u[LDW];
    #pragma unroll
    for (int k = 0; k < NS; ++k) u[k] = TsT[k*MS + cc];
    u[150] = 0.0f; u[151] = 0.0f;
    float qa = 0.0f, ra = 0.0f;
    #pragma unroll
    for (int k = 0; k < NS; ++k) {
        const int base = rs_off(k) - (k & ~3);
        float uk = u[k] * Up[base + k];      // diag slot holds 1/d
        qa += uk * uk;
        ra += uk * yv[k];
        const int kp = k + 1;
        const int ka = (kp + 3) & ~3;
        #pragma unroll
        for (int t = kp; t < ((ka < NS) ? ka : NS); ++t)
            u[t] -= Up[base + t] * uk;
        #pragma unroll
        for (int t = ka; t < NS; t += 4) {
            float4 w = *(const float4*)&Up[base + t];
            u[t+0] -= w.x * uk; u[t+1] -= w.y * uk;
            u[t+2] -= w.z * uk; u[t+3] -= w.w * uk;
        }
    }
    if (active) {
        q[j*MS + c] = qa;
        R[j*MS + c] = ra;
    }
}

// K5: outputs. yPred[is][it] = sum_j A[it][j]*R[j][is];
//              yVar [is][it] = sig2 - sum_j A[it][j]^2 * q[j][is]
__global__ void finalize(const float* __restrict__ A, const float* __restrict__ q,
                         const float* __restrict__ R, const float* __restrict__ lsv,
                         float* __restrict__ out) {
    int idx = blockIdx.x * blockDim.x + threadIdx.x;
    if (idx >= MS * MT) return;
    int is = idx / MT, it = idx % MT;
    float sp = 0.0f, sv = 0.0f;
    for (int j = 0; j < NT; ++j) {
        float a = A[it*NT + j];
        sp += a * R[j*MS + is];
        sv += a*a * q[j*MS + is];
    }
    float sigv = expf(lsv[0]);
    out[idx] = sp;
    out[MS*MT + idx] = sigv - sv;
}

extern "C" void kernel_launch(void* const* d_in, const int* in_sizes, int n_in,
                              void* d_out, int out_size, void* d_ws, size_t ws_size,
                              hipStream_t stream) {
    const float* sc  = (const float*)d_in[0];   // 150x3
    const float* tc  = (const float*)d_in[1];   // 40x1
    const float* st  = (const float*)d_in[2];   // 150x40
    const float* tsc = (const float*)d_in[3];   // 200x3
    const float* ttc = (const float*)d_in[4];   // 30x1
    const float* lll = (const float*)d_in[5];
    const float* lle = (const float*)d_in[6];
    const float* llt = (const float*)d_in[7];
    const float* lnv = (const float*)d_in[8];
    const float* lsv = (const float*)d_in[9];
    float* out = (float*)d_out;

    float* ws   = (float*)d_ws;
    float* S    = ws;                 // 22500
    float* T    = S    + 22500;       // 1600
    float* TsT  = T    + 1600;        // 30000
    float* Tt   = TsT  + 30000;       // 1200
    float* Vt   = Tt   + 1200;        // 1600
    float* wt   = Vt   + 1600;        // 40
    float* Amat = wt   + 40;          // 1200
    float* q    = Amat + 1200;        // 8000
    float* R    = q    + 8000;        // 8000
    float* yg   = R    + 8000;        // 40*152 = 6080
    float* Ug   = yg   + 6080;        // 40*11848 = 473920

    int total1 = NS*NS + NT*NT + NS*MS + MT*NT;   // 55300
    hipLaunchKernelGGL(build_kernels, dim3((total1 + 255)/256), dim3(256), 0, stream,
                       sc, tc, tsc, ttc, lll, lle, llt, S, T, TsT, Tt);
    hipLaunchKernelGGL(jacobi, dim3(1), dim3(256), 0, stream, T, Tt, Vt, wt, Amat);
    hipLaunchKernelGGL(chol40, dim3(NT), dim3(256), 0, stream,
                       S, wt, Vt, st, lnv, Ug, yg);
    hipLaunchKernelGGL(trsm160, dim3(NT*4), dim3(64), 0, stream,
                       Ug, yg, TsT, q, R);
    hipLaunchKernelGGL(finalize, dim3((MS*MT + 255)/256), dim3(256), 0, stream,
                       Amat, q, R, lsv, out);
}

// Round 9
// 535.140 us; speedup vs baseline: 1.6451x; 1.0597x over previous
//
#include <hip/hip_runtime.h>
#include <math.h>

#define NS 150
#define LDW 152
#define NPACK 11848   // packed upper-tri floats (rows 16B-aligned)
#define NT 40
#define MS 200
#define MT 30
#define N_SWEEPS 6
#define ROUNDS (N_SWEEPS*(NT-1))
#define JITTER 0.1f

// packed upper-tri storage: row r holds cols [r&~3, 152), 16B-aligned start.
__device__ __forceinline__ int rs_off(int r) {
    int g = r >> 2, rm = r & 3;
    return LDW * r - 8 * g * (g - 1) - 4 * rm * g;
}

__device__ __forceinline__ void jac_params(const float A[NT][NT+1], float4* dst,
                                           int i, int rr) {
    int i0 = i, i1 = NT - 1 - i;
    int p = (i0 == 0) ? 0 : ((i0 - 1 + rr) % (NT - 1)) + 1;
    int q = ((i1 - 1 + rr) % (NT - 1)) + 1;
    if (p > q) { int tsw = p; p = q; q = tsw; }
    float app = A[p][p], aqq = A[q][q], apq = A[p][q];
    float c, s;
    if (apq == 0.0f) { c = 1.0f; s = 0.0f; }
    else {
        float tau = (aqq - app) / (2.0f * apq);
        float tt = ((tau >= 0.0f) ? 1.0f : -1.0f) / (fabsf(tau) + sqrtf(1.0f + tau*tau));
        c = rsqrtf(1.0f + tt*tt);
        s = tt * c;
    }
    dst[i] = make_float4(c, s, __int_as_float(p), __int_as_float(q));
}

// K1: 1 block, 256 threads. Builds T (WITH temporal jitter) from tc in LDS, runs
//     the R5-proven cyclic Jacobi. Tail: wt, G = V^T stData^T, Amat = Tt*V.
__global__ void __launch_bounds__(256) jacobi_all(
        const float* __restrict__ tc, const float* __restrict__ ttc,
        const float* __restrict__ st, const float* __restrict__ llt,
        float* __restrict__ wt, float* __restrict__ G, float* __restrict__ Amat) {
    __shared__ __align__(16) float A[NT][NT + 1];
    __shared__ __align__(16) float Vts[NT][44];     // Vts[j][k] = V[k][j]
    __shared__ __align__(16) float4 prm[2][NT/2];   // (c, s, bits(p), bits(q))
    __shared__ float tcs[NT];
    __shared__ __align__(16) float sts[NS*NT];
    __shared__ float Tts[MT*NT];
    int tid = threadIdx.x;
    float ilt2 = expf(-2.0f * llt[0]);
    if (tid < NT) tcs[tid] = tc[tid];
    for (int t4 = tid * 4; t4 < NS*NT; t4 += 1024)
        *(float4*)&sts[t4] = *(const float4*)&st[t4];
    __syncthreads();
    for (int idx = tid; idx < NT*NT; idx += 256) {
        int i = idx / NT, jj = idx - i*NT;
        float dt = tcs[i] - tcs[jj];
        float v = expf(-dt*dt*ilt2);
        if (i == jj) v += JITTER;
        A[i][jj] = v;
    }
    for (int idx = tid; idx < NT*44; idx += 256) {
        int jr = idx / 44, k = idx - jr*44;
        Vts[jr][k] = (jr == k) ? 1.0f : 0.0f;
    }
    __syncthreads();
    if (tid >= 200 && tid < 220) jac_params(A, prm[0], tid - 200, 0);
    __syncthreads();
    for (int rd = 0; rd < ROUNDS; ++rd) {
        const float4* cur = prm[rd & 1];
        float4* nxt = prm[(rd + 1) & 1];
        // fused left+right rotation on A (in place): 400 disjoint 2x2 blocks
        for (int t = tid; t < 400; t += 256) {
            int bi = t / 20, bj = t - bi*20;
            float4 Pi = cur[bi], Pj = cur[bj];
            int pi = __float_as_int(Pi.z), qi = __float_as_int(Pi.w);
            int pj = __float_as_int(Pj.z), qj = __float_as_int(Pj.w);
            float ci = Pi.x, si = Pi.y, cj = Pj.x, sj = Pj.y;
            float a00 = A[pi][pj], a01 = A[pi][qj], a10 = A[qi][pj], a11 = A[qi][qj];
            float b00 = ci*a00 - si*a10, b01 = ci*a01 - si*a11;
            float b10 = si*a00 + ci*a10, b11 = si*a01 + ci*a11;
            A[pi][pj] = cj*b00 - sj*b01; A[pi][qj] = sj*b00 + cj*b01;
            A[qi][pj] = cj*b10 - sj*b11; A[qi][qj] = sj*b10 + cj*b11;
        }
        __syncthreads();
        // V update (doesn't touch A) in parallel with params for next round
        if (tid < 200) {
            int pr = tid / 10, ch = (tid - pr*10) << 2;
            float4 P = cur[pr];
            int pj = __float_as_int(P.z), qj = __float_as_int(P.w);
            float c = P.x, s = P.y;
            float4 vp = *(float4*)&Vts[pj][ch];
            float4 vq = *(float4*)&Vts[qj][ch];
            float4 np, nq;
            np.x = c*vp.x - s*vq.x; nq.x = s*vp.x + c*vq.x;
            np.y = c*vp.y - s*vq.y; nq.y = s*vp.y + c*vq.y;
            np.z = c*vp.z - s*vq.z; nq.z = s*vp.z + c*vq.z;
            np.w = c*vp.w - s*vq.w; nq.w = s*vp.w + c*vq.w;
            *(float4*)&Vts[pj][ch] = np;
            *(float4*)&Vts[qj][ch] = nq;
        } else if (tid < 220) {
            jac_params(A, nxt, tid - 200, (rd + 1) % (NT - 1));
        }
        __syncthreads();
    }
    if (tid < NT) wt[tid] = A[tid][tid];
    for (int idx = tid; idx < NT*NS; idx += 256) {
        int jj = idx / NS, r = idx - jj*NS;
        float acc = 0.0f;
        for (int t = 0; t < NT; ++t) acc += Vts[jj][t] * sts[r*NT + t];
        G[idx] = acc;
    }
    for (int idx = tid; idx < MT*NT; idx += 256) {
        int it = idx / NT, t2 = idx - it*NT;
        float dt = ttc[it] - tcs[t2];
        Tts[idx] = expf(-dt*dt*ilt2);
    }
    __syncthreads();
    for (int idx = tid; idx < MT*NT; idx += 256) {
        int it = idx / NT, jj = idx - it*NT;
        float s = 0.0f;
        for (int t2 = 0; t2 < NT; ++t2) s += Tts[it*NT + t2] * Vts[jj][t2];
        Amat[idx] = s;
    }
}

// K2: 40 blocks. Builds M_j = wtj*(S + JITTER*I) + nv*I from coords into packed
//     LDS (RHS g as col 150), rank-4 panel factorization (pre-eliminated panel, 2
//     barriers/panel), in-LDS scaling, then fused trsm over 200 test cols.
__global__ void __launch_bounds__(256, 1) chol_solve_all(
        const float* __restrict__ sc, const float* __restrict__ tsc,
        const float* __restrict__ lll, const float* __restrict__ lle,
        const float* __restrict__ lnv, const float* __restrict__ wtg,
        const float* __restrict__ G, float* __restrict__ q, float* __restrict__ R) {
    __shared__ __align__(16) float Mp[NPACK];
    __shared__ __align__(16) float Pr[4][LDW];
    __shared__ float invs[4];
    __shared__ float dvs[NS];
    __shared__ float scs[NS*3];
    __shared__ float tscs[MS*3];
    int j = blockIdx.x, tid = threadIdx.x;
    float wtj = wtg[j];
    float nv = expf(lnv[0]);
    float ill2 = expf(-2.0f * lll[0]);
    float ile2 = expf(-2.0f * lle[0]);
    for (int t = tid; t < NS*3; t += 256) scs[t] = sc[t];
    for (int t = tid; t < MS*3; t += 256) tscs[t] = tsc[t];
    __syncthreads();
    for (int idx = tid; idx < NS*LDW; idx += 256) {
        int r = idx / LDW, c = idx - r*LDW;
        int rbase = r & ~3;
        if (c < rbase) continue;
        float v;
        if (c < NS) {
            float d0 = scs[r*3+0] - scs[c*3+0];
            float d1 = scs[r*3+1] - scs[c*3+1];
            float d2 = scs[r*3+2] - scs[c*3+2];
            v = wtj * expf(-((d0*d0 + d1*d1)*ill2 + d2*d2*ile2));
            // reference: spatial_K = SE + JITTER*I, so M diag gets wtj*JITTER too
            if (c == r) v += wtj * JITTER + nv;
        } else if (c == NS) {
            v = G[j*NS + r];
        } else {
            v = 0.0f;
        }
        Mp[rs_off(r) + c - rbase] = v;
    }
    __syncthreads();
    for (int k0 = 0; k0 < NS - 1; k0 += 4) {
        int P = NS - k0; if (P > 4) P = 4;
        int W4 = (LDW - k0) >> 2;
        // phase A: stage + pre-eliminate panel rows into Pr (single wave)
        if (tid < W4) {
            int o0 = rs_off(k0);
            int o1 = (P > 1) ? rs_off(k0+1) : o0;
            int o2 = (P > 2) ? rs_off(k0+2) : o0;
            int o3 = (P > 3) ? rs_off(k0+3) : o0;
            float b00 = Mp[o0+0];
            float b01 = (P>1)? Mp[o0+1] : 0.f;
            float b02 = (P>2)? Mp[o0+2] : 0.f;
            float b03 = (P>3)? Mp[o0+3] : 0.f;
            float b11 = (P>1)? Mp[o1+1] : 1.f;
            float b12 = (P>2)? Mp[o1+2] : 0.f;
            float b13 = (P>3)? Mp[o1+3] : 0.f;
            float b22 = (P>2)? Mp[o2+2] : 1.f;
            float b23 = (P>3)? Mp[o2+3] : 0.f;
            float b33 = (P>3)? Mp[o3+3] : 1.f;
            float i0 = 1.f/b00;
            float l10 = b01*i0, l20 = b02*i0, l30 = b03*i0;
            float c11 = b11 - l10*b01;
            float i1 = 1.f/c11;
            float c12 = b12 - l10*b02, c13 = b13 - l10*b03;
            float l21 = c12*i1, l31 = c13*i1;
            float c22 = b22 - l20*b02 - l21*c12;
            float i2 = 1.f/c22;
            float c23 = b23 - l20*b03 - l21*c13;
            float l32 = c23*i2;
            float c33 = b33 - l30*b03 - l31*c13 - l32*c23;
            float i3 = 1.f/c33;
            int C = tid << 2;
            float4 z = make_float4(0,0,0,0);
            float4 m0 = *(float4*)&Mp[o0 + C];
            float4 m1 = (P>1)? *(float4*)&Mp[o1 + C] : z;
            float4 m2 = (P>2)? *(float4*)&Mp[o2 + C] : z;
            float4 m3 = (P>3)? *(float4*)&Mp[o3 + C] : z;
            m1.x -= l10*m0.x; m1.y -= l10*m0.y; m1.z -= l10*m0.z; m1.w -= l10*m0.w;
            m2.x -= l20*m0.x + l21*m1.x; m2.y -= l20*m0.y + l21*m1.y;
            m2.z -= l20*m0.z + l21*m1.z; m2.w -= l20*m0.w + l21*m1.w;
            m3.x -= l30*m0.x + l31*m1.x + l32*m2.x;
            m3.y -= l30*m0.y + l31*m1.y + l32*m2.y;
            m3.z -= l30*m0.z + l31*m1.z + l32*m2.z;
            m3.w -= l30*m0.w + l31*m1.w + l32*m2.w;
            *(float4*)&Pr[0][C] = m0;
            *(float4*)&Pr[1][C] = m1;
            *(float4*)&Pr[2][C] = m2;
            *(float4*)&Pr[3][C] = m3;
            if (tid == 0) { invs[0]=i0; invs[1]=i1; invs[2]=i2; invs[3]=i3; }
        }
        __syncthreads();
        // phase B: rank-P trailing update, thread-per-row, contiguous f4 sweep
        float iv0 = invs[0], iv1 = invs[1], iv2 = invs[2], iv3 = invs[3];
        for (int r = k0 + 1 + tid; r < NS; r += 256) {
            int rc = r - k0;
            int E = rc < P ? rc : P;
            float f0 = Pr[0][rc] * iv0;
            float f1 = (E > 1) ? Pr[1][rc] * iv1 : 0.f;
            float f2 = (E > 2) ? Pr[2][rc] * iv2 : 0.f;
            float f3 = (E > 3) ? Pr[3][rc] * iv3 : 0.f;
            int rbase = r & ~3;
            int ro = rs_off(r) - rbase;
            for (int C = rbase; C < LDW; C += 4) {
                int pc = C - k0;
                float4 v  = *(float4*)&Mp[ro + C];
                float4 p0 = *(float4*)&Pr[0][pc];
                float4 p1 = *(float4*)&Pr[1][pc];
                float4 p2 = *(float4*)&Pr[2][pc];
                float4 p3 = *(float4*)&Pr[3][pc];
                v.x -= f0*p0.x + f1*p1.x + f2*p2.x + f3*p3.x;
                v.y -= f0*p0.y + f1*p1.y + f2*p2.y + f3*p3.y;
                v.z -= f0*p0.z + f1*p1.z + f2*p2.z + f3*p3.z;
                v.w -= f0*p0.w + f1*p1.w + f2*p2.w + f3*p3.w;
                *(float4*)&Mp[ro + C] = v;
            }
        }
        __syncthreads();
    }
    // scale in place: diag slot = 1/d, cols>r (incl. RHS col 150 -> y) *= 1/d
    for (int r = tid; r < NS; r += 256)
        dvs[r] = rsqrtf(Mp[rs_off(r) + r - (r & ~3)]);
    __syncthreads();
    for (int idx = tid; idx < NS*LDW; idx += 256) {
        int r = idx / LDW, c = idx - r*LDW;
        int rbase = r & ~3;
        if (c < rbase) continue;
        int t = rs_off(r) + c - rbase;
        float dvr = dvs[r];
        if (c == r) Mp[t] = dvr;
        else if (c > r) Mp[t] *= dvr;
    }
    __syncthreads();
    // fused trsm: thread-per-test-column, u[] in registers, broadcast LDS rows.
    // u has LDW=152 entries: the last float4 tail (t=148) writes u[150],u[151].
    if (tid < MS) {
        float tx = tscs[tid*3+0], ty = tscs[tid*3+1], tz = tscs[tid*3+2];
        float u[LDW];
        #pragma unroll
        for (int k = 0; k < NS; ++k) {
            float d0 = tx - scs[k*3+0];
            float d1 = ty - scs[k*3+1];
            float d2 = tz - scs[k*3+2];
            u[k] = expf(-((d0*d0 + d1*d1)*ill2 + d2*d2*ile2));
        }
        u[150] = 0.0f; u[151] = 0.0f;
        float qa = 0.0f, ra = 0.0f;
        #pragma unroll
        for (int k = 0; k < NS; ++k) {
            const int base = rs_off(k) - (k & ~3);
            float uk = u[k] * Mp[base + k];     // diag slot = 1/d
            qa += uk * uk;
            ra += uk * Mp[base + 150];          // scaled RHS = y_k
            const int kp = k + 1;
            const int ka = (kp + 3) & ~3;
            #pragma unroll
            for (int t = kp; t < ((ka < NS) ? ka : NS); ++t)
                u[t] -= Mp[base + t] * uk;
            #pragma unroll
            for (int t = ka; t < NS; t += 4) {
                float4 w = *(const float4*)&Mp[base + t];
                u[t+0] -= w.x * uk; u[t+1] -= w.y * uk;
                u[t+2] -= w.z * uk; u[t+3] -= w.w * uk;
            }
        }
        q[j*MS + tid] = qa;
        R[j*MS + tid] = ra;
    }
}

// K3: outputs. yPred[is][it] = sum_j A[it][j]*R[j][is];
//              yVar [is][it] = sig2 - sum_j A[it][j]^2 * q[j][is]
__global__ void finalize(const float* __restrict__ A, const float* __restrict__ q,
                         const float* __restrict__ R, const float* __restrict__ lsv,
                         float* __restrict__ out) {
    int idx = blockIdx.x * blockDim.x + threadIdx.x;
    if (idx >= MS * MT) return;
    int is = idx / MT, it = idx % MT;
    float sp = 0.0f, sv = 0.0f;
    for (int j = 0; j < NT; ++j) {
        float a = A[it*NT + j];
        sp += a * R[j*MS + is];
        sv += a*a * q[j*MS + is];
    }
    float sigv = expf(lsv[0]);
    out[idx] = sp;
    out[MS*MT + idx] = sigv - sv;
}

extern "C" void kernel_launch(void* const* d_in, const int* in_sizes, int n_in,
                              void* d_out, int out_size, void* d_ws, size_t ws_size,
                              hipStream_t stream) {
    const float* sc  = (const float*)d_in[0];   // 150x3
    const float* tc  = (const float*)d_in[1];   // 40x1
    const float* st  = (const float*)d_in[2];   // 150x40
    const float* tsc = (const float*)d_in[3];   // 200x3
    const float* ttc = (const float*)d_in[4];   // 30x1
    const float* lll = (const float*)d_in[5];
    const float* lle = (const float*)d_in[6];
    const float* llt = (const float*)d_in[7];
    const float* lnv = (const float*)d_in[8];
    const float* lsv = (const float*)d_in[9];
    float* out = (float*)d_out;

    float* ws   = (float*)d_ws;
    float* wt   = ws;                 // 40
    float* G    = wt   + 40;          // 40*150 = 6000
    float* Amat = G    + 6000;        // 30*40 = 1200
    float* q    = Amat + 1200;        // 8000
    float* R    = q    + 8000;        // 8000

    hipLaunchKernelGGL(jacobi_all, dim3(1), dim3(256), 0, stream,
                       tc, ttc, st, llt, wt, G, Amat);
    hipLaunchKernelGGL(chol_solve_all, dim3(NT), dim3(256), 0, stream,
                       sc, tsc, lll, lle, lnv, wt, G, q, R);
    hipLaunchKernelGGL(finalize, dim3((MS*MT + 255)/256), dim3(256), 0, stream,
                       Amat, q, R, lsv, out);
}